// Round 13
// baseline (92.046 us; speedup 1.0000x reference)
//
#include <hip/hip_runtime.h>
#include <math.h>

// NEAT forward, round 13.
//  - prep: trivial transpose/convert (R12 — best measured total).
//  - fwd: R12 + cross-barrier record prefetch: after the last gather of
//    layer L (r[] regs dead), issue loads for 8 of layer L+1's 16 record
//    quads; the barrier + act writes hide the L2 latency that was exposed
//    at each layer top. rn[8] = 32 VGPR transient keeps peak < 128 so
//    4 waves/SIMD occupancy is preserved.
//  - DS-pipe model says fwd is ~at its roofline: 8448 b64 gathers x ~8cyc
//    + 42k conflict cyc ~= 109k cyc/CU ~= measured. This targets the only
//    non-DS exposure left (~1.5-2 us of record-load latency).

#define N_IN    512
#define NLAYER  9
#define DEG     64
#define BATCH   1024
#define BPB     4
#define THREADS 1024
#define TOTAL_N 8960            // 512 + 8*1024 + 256
#define N_OUT   256
#define NREC    135168          // E_TOTAL/4 ; = 528 * 256 exactly

union H4 { uint2 u; _Float16 h[4]; };
union H2 { unsigned u; _Float16 h[2]; };
union HS { _Float16 h; unsigned short s; };

// ---- prep: one thread = one record, no sort ----
__global__ __launch_bounds__(256)
void neat_prep(const float* __restrict__ wts,
               const int*   __restrict__ sidx,
               uint4*       __restrict__ rec)
{
    const int r = blockIdx.x * 256 + threadIdx.x;   // 0..135167, grid exact
    const int l = r >> 14;                          // layer (8 = last)
    const int j = r & 16383;
    const int n = ((j >> 10) << 6) | (j & 63);      // neuron within layer
    const int q = (j >> 6) & 15;                    // quad
    const int e0 = (l << 16) + (n << 6) + (q << 2);

    const int4   s4 = *reinterpret_cast<const int4*>(sidx + e0);
    const float4 w4 = *reinterpret_cast<const float4*>(wts + e0);
    HS h0, h1, h2, h3;
    h0.h = (_Float16)w4.x; h1.h = (_Float16)w4.y;
    h2.h = (_Float16)w4.z; h3.h = (_Float16)w4.w;

    uint4 o;
    o.x = ((unsigned)s4.x & 0xffffu) | ((unsigned)s4.y << 16);
    o.y = ((unsigned)s4.z & 0xffffu) | ((unsigned)s4.w << 16);
    o.z = (unsigned)h0.s | ((unsigned)h1.s << 16);
    o.w = (unsigned)h2.s | ((unsigned)h3.s << 16);
    rec[r] = o;                                     // coalesced
}

__global__ __launch_bounds__(THREADS, 4)
void neat_fwd(const float* __restrict__ in,
              const uint4* __restrict__ rec,
              float*       __restrict__ out)
{
    __shared__ _Float16 act[TOTAL_N * BPB];          // 71,680 B

    const int tid   = threadIdx.x;
    const int bbase = blockIdx.x * BPB;

    // ---- stage inputs (f32 -> f16) ----
    {
        const float* src = in + bbase * N_IN;
        for (int t = tid; t < BPB * N_IN; t += THREADS) {
            int j = t >> 9;
            int i = t & (N_IN - 1);
            act[i * BPB + j] = (_Float16)src[t];
        }
    }

    const int lanebase = ((tid >> 6) << 10) + (tid & 63);

    // preload layer 0 records (issued before the staging barrier)
    uint4 r[16];
    {
        const uint4* rp = rec + lanebase;
        #pragma unroll
        for (int q = 0; q < 16; ++q) r[q] = rp[q << 6];
    }
    __syncthreads();

    int recBase = 0;
    int nb      = N_IN;
    #pragma unroll 1
    for (int layer = 0; layer < NLAYER; ++layer) {
        const int n  = (layer < NLAYER - 1) ? 1024 : N_OUT;
        const int nn = (layer < NLAYER - 2) ? 1024 : N_OUT;   // next layer

        float accx = 0.f, accy = 0.f, accz = 0.f, accw = 0.f;
        if (tid < n) {
            #pragma unroll
            for (int q = 0; q < 16; ++q) {
                const uint4 r4 = r[q];
                H4 g0, g1, g2, g3;
                g0.u = *reinterpret_cast<const uint2*>(act + ((r4.x & 0xffffu) << 2));
                g1.u = *reinterpret_cast<const uint2*>(act + ((r4.x >> 16) << 2));
                g2.u = *reinterpret_cast<const uint2*>(act + ((r4.y & 0xffffu) << 2));
                g3.u = *reinterpret_cast<const uint2*>(act + ((r4.y >> 16) << 2));
                H2 wz, ww; wz.u = r4.z; ww.u = r4.w;
                const float w0 = (float)wz.h[0];
                const float w1 = (float)wz.h[1];
                const float w2 = (float)ww.h[0];
                const float w3 = (float)ww.h[1];
                accx = fmaf((float)g0.h[0], w0, accx);
                accy = fmaf((float)g0.h[1], w0, accy);
                accz = fmaf((float)g0.h[2], w0, accz);
                accw = fmaf((float)g0.h[3], w0, accw);
                accx = fmaf((float)g1.h[0], w1, accx);
                accy = fmaf((float)g1.h[1], w1, accy);
                accz = fmaf((float)g1.h[2], w1, accz);
                accw = fmaf((float)g1.h[3], w1, accw);
                accx = fmaf((float)g2.h[0], w2, accx);
                accy = fmaf((float)g2.h[1], w2, accy);
                accz = fmaf((float)g2.h[2], w2, accz);
                accw = fmaf((float)g2.h[3], w2, accw);
                accx = fmaf((float)g3.h[0], w3, accx);
                accy = fmaf((float)g3.h[1], w3, accy);
                accz = fmaf((float)g3.h[2], w3, accz);
                accw = fmaf((float)g3.h[3], w3, accw);
            }
        }

        // prefetch first 8 record-quads of next layer (r[0..7] regs dead)
        uint4 rn[8];
        const int recNext = recBase + (n << 4);
        if (layer < NLAYER - 1 && tid < nn) {
            const uint4* rp = rec + recNext + lanebase;
            #pragma unroll
            for (int q = 0; q < 8; ++q) rn[q] = rp[q << 6];
        }

        if (tid < n) {
            float4 sg;
            sg.x = 1.f / (1.f + __expf(-accx));
            sg.y = 1.f / (1.f + __expf(-accy));
            sg.z = 1.f / (1.f + __expf(-accz));
            sg.w = 1.f / (1.f + __expf(-accw));

            if (layer < NLAYER - 1) {
                H4 p;
                p.h[0] = (_Float16)sg.x; p.h[1] = (_Float16)sg.y;
                p.h[2] = (_Float16)sg.z; p.h[3] = (_Float16)sg.w;
                *reinterpret_cast<uint2*>(act + ((nb + tid) << 2)) = p.u;
            } else {
                float* op = out + tid;               // f32 output
                op[(bbase + 0) * N_OUT] = sg.x;
                op[(bbase + 1) * N_OUT] = sg.y;
                op[(bbase + 2) * N_OUT] = sg.z;
                op[(bbase + 3) * N_OUT] = sg.w;
            }
        }
        __syncthreads();

        if (layer < NLAYER - 1) {
            #pragma unroll
            for (int q = 0; q < 8; ++q) r[q] = rn[q];
            if (tid < nn) {
                const uint4* rp = rec + recNext + lanebase;
                #pragma unroll
                for (int q = 8; q < 16; ++q) r[q] = rp[q << 6];
            }
        }
        recBase = recNext;
        nb     += n;
    }
}

extern "C" void kernel_launch(void* const* d_in, const int* in_sizes, int n_in,
                              void* d_out, int out_size, void* d_ws, size_t ws_size,
                              hipStream_t stream)
{
    const float* in  = (const float*)d_in[0];
    const float* wts = (const float*)d_in[1];
    const int*   sx  = (const int*)d_in[2];
    float*       out = (float*)d_out;
    uint4*       rec = (uint4*)d_ws;    // 135,168 * 16 = 2,162,688 B

    neat_prep<<<NREC / 256, 256, 0, stream>>>(wts, sx, rec);
    neat_fwd<<<BATCH / BPB, THREADS, 0, stream>>>(in, rec, out);
}

// Round 14
// 48.679 us; speedup vs baseline: 1.8909x; 1.8909x over previous
//
#include <hip/hip_runtime.h>
#include <math.h>

// NEAT forward, round 14.
//  - fwd: byte-identical revert to R12 (R13's cross-barrier prefetch put
//    the record arrays in scratch: WRITE_SIZE 1MB -> 207MB, fwd 44 -> 88us.
//    Lesson: conditionally-assigned arrays + array copies => local memory).
//  - prep: coalesced-READ form. Thread r loads edges [4r,4r+4) (int4/float4
//    fully coalesced across the wave) and computes the scattered DESTINATION
//    record slot. R12's prep read at stride 256B (64 lines/wave-inst);
//    scattered 16-B writes are cheap (no latency exposure), scattered
//    reads are not.

#define N_IN    512
#define NLAYER  9
#define DEG     64
#define BATCH   1024
#define BPB     4
#define THREADS 1024
#define TOTAL_N 8960            // 512 + 8*1024 + 256
#define N_OUT   256
#define NREC    135168          // E_TOTAL/4 ; = 528 * 256 exactly

union H4 { uint2 u; _Float16 h[4]; };
union H2 { unsigned u; _Float16 h[2]; };
union HS { _Float16 h; unsigned short s; };

// ---- prep: coalesced reads, scattered record writes ----
__global__ __launch_bounds__(256)
void neat_prep(const float* __restrict__ wts,
               const int*   __restrict__ sidx,
               uint4*       __restrict__ rec)
{
    const int r  = blockIdx.x * 256 + threadIdx.x;  // 0..135167, grid exact
    const int e0 = r << 2;                          // coalesced source

    const int4   s4 = *reinterpret_cast<const int4*>(sidx + e0);
    const float4 w4 = *reinterpret_cast<const float4*>(wts + e0);
    HS h0, h1, h2, h3;
    h0.h = (_Float16)w4.x; h1.h = (_Float16)w4.y;
    h2.h = (_Float16)w4.z; h3.h = (_Float16)w4.w;

    uint4 o;
    o.x = ((unsigned)s4.x & 0xffffu) | ((unsigned)s4.y << 16);
    o.y = ((unsigned)s4.z & 0xffffu) | ((unsigned)s4.w << 16);
    o.z = (unsigned)h0.s | ((unsigned)h1.s << 16);
    o.w = (unsigned)h2.s | ((unsigned)h3.s << 16);

    // destination: rec[l*16384 + (n>>6)*1024 + q*64 + (n&63)]
    const int l = e0 >> 16;             // 64K edges per 1024-neuron layer
    const int n = (e0 >> 6) & 1023;     // neuron within layer
    const int q = (e0 >> 2) & 15;       // quad
    rec[(l << 14) + ((n >> 6) << 10) + (q << 6) + (n & 63)] = o;
}

__global__ __launch_bounds__(THREADS, 4)
void neat_fwd(const float* __restrict__ in,
              const uint4* __restrict__ rec,
              float*       __restrict__ out)
{
    __shared__ _Float16 act[TOTAL_N * BPB];          // 71,680 B

    const int tid   = threadIdx.x;
    const int bbase = blockIdx.x * BPB;

    // ---- stage inputs (f32 -> f16) ----
    {
        const float* src = in + bbase * N_IN;
        for (int t = tid; t < BPB * N_IN; t += THREADS) {
            int j = t >> 9;
            int i = t & (N_IN - 1);
            act[i * BPB + j] = (_Float16)src[t];
        }
    }
    __syncthreads();

    int recBase = 0;
    int nb      = N_IN;
    #pragma unroll 1
    for (int layer = 0; layer < NLAYER; ++layer) {
        const int n = (layer < NLAYER - 1) ? 1024 : N_OUT;
        if (tid < n) {
            const int neuron = tid;
            const uint4* rp = rec + recBase + ((neuron >> 6) << 10) + (neuron & 63);

            uint4 r[16];
            #pragma unroll
            for (int q = 0; q < 16; ++q) r[q] = rp[q << 6];

            float accx = 0.f, accy = 0.f, accz = 0.f, accw = 0.f;
            #pragma unroll
            for (int q = 0; q < 16; ++q) {
                const uint4 r4 = r[q];
                H4 g0, g1, g2, g3;
                g0.u = *reinterpret_cast<const uint2*>(act + ((r4.x & 0xffffu) << 2));
                g1.u = *reinterpret_cast<const uint2*>(act + ((r4.x >> 16) << 2));
                g2.u = *reinterpret_cast<const uint2*>(act + ((r4.y & 0xffffu) << 2));
                g3.u = *reinterpret_cast<const uint2*>(act + ((r4.y >> 16) << 2));
                H2 wz, ww; wz.u = r4.z; ww.u = r4.w;
                const float w0 = (float)wz.h[0];
                const float w1 = (float)wz.h[1];
                const float w2 = (float)ww.h[0];
                const float w3 = (float)ww.h[1];
                accx = fmaf((float)g0.h[0], w0, accx);
                accy = fmaf((float)g0.h[1], w0, accy);
                accz = fmaf((float)g0.h[2], w0, accz);
                accw = fmaf((float)g0.h[3], w0, accw);
                accx = fmaf((float)g1.h[0], w1, accx);
                accy = fmaf((float)g1.h[1], w1, accy);
                accz = fmaf((float)g1.h[2], w1, accz);
                accw = fmaf((float)g1.h[3], w1, accw);
                accx = fmaf((float)g2.h[0], w2, accx);
                accy = fmaf((float)g2.h[1], w2, accy);
                accz = fmaf((float)g2.h[2], w2, accz);
                accw = fmaf((float)g2.h[3], w2, accw);
                accx = fmaf((float)g3.h[0], w3, accx);
                accy = fmaf((float)g3.h[1], w3, accy);
                accz = fmaf((float)g3.h[2], w3, accz);
                accw = fmaf((float)g3.h[3], w3, accw);
            }

            float4 sg;
            sg.x = 1.f / (1.f + __expf(-accx));
            sg.y = 1.f / (1.f + __expf(-accy));
            sg.z = 1.f / (1.f + __expf(-accz));
            sg.w = 1.f / (1.f + __expf(-accw));

            if (layer < NLAYER - 1) {
                H4 p;
                p.h[0] = (_Float16)sg.x; p.h[1] = (_Float16)sg.y;
                p.h[2] = (_Float16)sg.z; p.h[3] = (_Float16)sg.w;
                *reinterpret_cast<uint2*>(act + ((nb + neuron) << 2)) = p.u;
            } else {
                float* op = out + neuron;            // f32 output
                op[(bbase + 0) * N_OUT] = sg.x;
                op[(bbase + 1) * N_OUT] = sg.y;
                op[(bbase + 2) * N_OUT] = sg.z;
                op[(bbase + 3) * N_OUT] = sg.w;
            }
        }
        __syncthreads();
        recBase += n << 4;
        nb      += n;
    }
}

extern "C" void kernel_launch(void* const* d_in, const int* in_sizes, int n_in,
                              void* d_out, int out_size, void* d_ws, size_t ws_size,
                              hipStream_t stream)
{
    const float* in  = (const float*)d_in[0];
    const float* wts = (const float*)d_in[1];
    const int*   sx  = (const int*)d_in[2];
    float*       out = (float*)d_out;
    uint4*       rec = (uint4*)d_ws;    // 135,168 * 16 = 2,162,688 B

    neat_prep<<<NREC / 256, 256, 0, stream>>>(wts, sx, rec);
    neat_fwd<<<BATCH / BPB, THREADS, 0, stream>>>(in, rec, out);
}